// Round 14
// baseline (136.161 us; speedup 1.0000x reference)
//
#include <hip/hip_runtime.h>

#define DIM 1024
#define NHEADS 16
#define HD 64
#define SEQ 2048
#define BATCH 2
#define MROWS (BATCH*SEQ)
#define QKVLD 3072

typedef _Float16 h16;
typedef __attribute__((ext_vector_type(2))) _Float16 h16x2;
typedef __attribute__((ext_vector_type(2))) __fp16 fp16x2;
typedef __attribute__((ext_vector_type(4))) _Float16 h16x4;
typedef __attribute__((ext_vector_type(8))) _Float16 h16x8;
typedef __attribute__((ext_vector_type(4))) float f32x4;
typedef __attribute__((ext_vector_type(16))) float f32x16;

union U2 { fp16x2 g; h16x2 h; unsigned u; };

#define CBAR() do { asm volatile("" ::: "memory"); __builtin_amdgcn_s_barrier(); \
                    asm volatile("" ::: "memory"); } while (0)

// ---------------- fused prep: cvt x, cvt weights (packed QKV), rope table ----------------
__global__ __launch_bounds__(256) void prep_k(
    const float* __restrict__ x,  const float* __restrict__ wq,
    const float* __restrict__ wk, const float* __restrict__ wv,
    const float* __restrict__ wo,
    h16* __restrict__ xh, h16* __restrict__ wqkvh, h16* __restrict__ woh,
    float2* __restrict__ rope)
{
    const int NX = MROWS * DIM / 4;      // 1048576
    const int NW = DIM * DIM / 4;        // 262144 = 2^18
    int gid = blockIdx.x * 256 + threadIdx.x;
    if (gid < NX) {
        float4 v = *reinterpret_cast<const float4*>(x + (size_t)gid * 4);
        h16x4 o; o.x=(h16)v.x; o.y=(h16)v.y; o.z=(h16)v.z; o.w=(h16)v.w;
        *reinterpret_cast<h16x4*>(xh + (size_t)gid * 4) = o;
    } else if (gid < NX + 3 * NW) {
        int j = gid - NX;
        int w = j >> 18, e = j & (NW - 1);
        const float* s = (w == 0) ? wq : (w == 1) ? wk : wv;
        float4 v = *reinterpret_cast<const float4*>(s + (size_t)e * 4);
        h16x4 o; o.x=(h16)v.x; o.y=(h16)v.y; o.z=(h16)v.z; o.w=(h16)v.w;
        *reinterpret_cast<h16x4*>(wqkvh + (size_t)w * DIM * DIM + (size_t)e * 4) = o;
    } else if (gid < NX + 4 * NW) {
        int e = gid - NX - 3 * NW;
        float4 v = *reinterpret_cast<const float4*>(wo + (size_t)e * 4);
        h16x4 o; o.x=(h16)v.x; o.y=(h16)v.y; o.z=(h16)v.z; o.w=(h16)v.w;
        *reinterpret_cast<h16x4*>(woh + (size_t)e * 4) = o;
    } else {
        int t = gid - NX - 4 * NW;      // 0..65535
        int s = t >> 5, j = t & 31;
        float inv = powf(10000.0f, -(float)j / 32.0f);
        float ang = (float)s * inv;
        rope[t] = make_float2(cosf(ang), sinf(ang));
    }
}

// ---------------- QKV GEMM: 256x256 tile, 8-wave, deep counted-vmcnt pipeline (R12-verified) ----------------
__global__ __launch_bounds__(512, 1) void gemm256_qkv(
    const h16* __restrict__ A, const h16* __restrict__ Bw,
    h16* __restrict__ C, const float2* __restrict__ rope)
{
    __shared__ h16 As[2][256][64];   // 64 KB
    __shared__ h16 Bs[2][256][64];   // 64 KB
    const int tid = threadIdx.x, wave = tid >> 6, lane = tid & 63;
    const int lr = lane & 15, lg = lane >> 4;
    const int wm = wave >> 2, wn = wave & 3;          // 2 x 4 wave grid
    const int xr = blockIdx.x & 7, jr = blockIdx.x >> 3;   // rect-per-XCD
    const int bm = ((xr >> 1) << 2) + (jr & 3);
    const int bn = (xr & 1) * 6 + (jr >> 2);
    const int m0 = bm << 8, n0 = bn << 8;

    const int srl = lane >> 3;            // 0..7
    const int sgc = ((lane & 7) ^ srl) << 3;

#define STAGE_HALF(buf, k0_, h_) do {                                               \
    _Pragma("unroll")                                                               \
    for (int j_ = 0; j_ < 2; ++j_) {                                                \
        int rl_ = ((h_) & 1) * 128 + (j_ * 8 + wave) * 8;                           \
        if ((h_) < 2) {                                                             \
            const h16* g_ = A + (size_t)(m0 + rl_ + srl) * DIM + (k0_) + sgc;       \
            __builtin_amdgcn_global_load_lds(                                       \
                (const __attribute__((address_space(1))) void*)g_,                  \
                (__attribute__((address_space(3))) void*)(&As[buf][rl_][0]), 16, 0, 0); \
        } else {                                                                    \
            const h16* g_ = Bw + (size_t)(n0 + rl_ + srl) * DIM + (k0_) + sgc;      \
            __builtin_amdgcn_global_load_lds(                                       \
                (const __attribute__((address_space(1))) void*)g_,                  \
                (__attribute__((address_space(3))) void*)(&Bs[buf][rl_][0]), 16, 0, 0); \
        }                                                                           \
    }                                                                               \
} while (0)

    f32x4 acc[8][4];
#pragma unroll
    for (int i = 0; i < 8; ++i)
#pragma unroll
        for (int j = 0; j < 4; ++j) acc[i][j] = (f32x4){0.f, 0.f, 0.f, 0.f};

    const int NT = DIM >> 6;   // 16
#pragma unroll
    for (int h = 0; h < 4; ++h) STAGE_HALF(0, 0, h);

    int cur = 0;
    for (int t = 0; t < NT; ++t) {
        const int k0n = (t + 1) << 6;
        const bool pf = (t + 1 < NT);
        if (pf) {
#pragma unroll
            for (int h = 0; h < 4; ++h) STAGE_HALF(cur ^ 1, k0n, h);
        }
        if (pf) asm volatile("s_waitcnt vmcnt(8)" ::: "memory");
        else    asm volatile("s_waitcnt vmcnt(0)" ::: "memory");
        CBAR();
        h16x8 bfr[4][2];
#pragma unroll
        for (int ni = 0; ni < 4; ++ni)
#pragma unroll
            for (int ks = 0; ks < 2; ++ks) {
                int r = wn * 64 + ni * 16 + lr;
                int cpos = ((ks << 2) + lg) ^ (lr & 7);
                bfr[ni][ks] = *(const h16x8*)&Bs[cur][r][cpos << 3];
            }
#pragma unroll
        for (int half = 0; half < 2; ++half) {
            h16x8 afr[4][2];
#pragma unroll
            for (int e = 0; e < 4; ++e)
#pragma unroll
                for (int ks = 0; ks < 2; ++ks) {
                    int r = wm * 128 + (half * 4 + e) * 16 + lr;
                    int cpos = ((ks << 2) + lg) ^ (lr & 7);
                    afr[e][ks] = *(const h16x8*)&As[cur][r][cpos << 3];
                }
            __builtin_amdgcn_s_setprio(1);
#pragma unroll
            for (int e = 0; e < 4; ++e)
#pragma unroll
                for (int ni = 0; ni < 4; ++ni)
#pragma unroll
                    for (int ks = 0; ks < 2; ++ks)
                        acc[half * 4 + e][ni] = __builtin_amdgcn_mfma_f32_16x16x32_f16(
                            afr[e][ks], bfr[ni][ks], acc[half * 4 + e][ni], 0, 0, 0);
            __builtin_amdgcn_s_setprio(0);
        }
        CBAR();
        cur ^= 1;
    }
#undef STAGE_HALF

    const int region = n0 >> 10;       // 0=Q, 1=K, 2=V
    if (region == 2) {
#pragma unroll
        for (int mi = 0; mi < 8; ++mi)
#pragma unroll
            for (int i = 0; i < 4; ++i) {
                int row = m0 + wm * 128 + mi * 16 + lg * 4 + i;
#pragma unroll
                for (int ni = 0; ni < 4; ++ni) {
                    int col = n0 + wn * 64 + ni * 16 + lr;
                    C[(size_t)row * QKVLD + col] = (h16)acc[mi][ni][i];
                }
            }
    } else {
#pragma unroll
        for (int mi = 0; mi < 8; ++mi)
#pragma unroll
            for (int i = 0; i < 4; ++i) {
                int row = m0 + wm * 128 + mi * 16 + lg * 4 + i;
                int s = row & (SEQ - 1);
#pragma unroll
                for (int ni = 0; ni < 4; ++ni) {
                    int col = n0 + wn * 64 + ni * 16 + lr;
                    int d = col & 63;
                    float2 cs = rope[(s << 5) + (d & 31)];
                    float v  = acc[mi][ni][i];
                    float vp = acc[mi][ni ^ 2][i];
                    float rh = (d < 32) ? -vp : vp;
                    C[(size_t)row * QKVLD + col] = (h16)(v * cs.x + rh * cs.y);
                }
            }
    }
}

// ---------------- out-proj GEMM: 128x128, deep burst pipeline + rect swizzle (R13-verified) ----------------
__global__ __launch_bounds__(256) void gemm_out(
    const h16* __restrict__ A, const h16* __restrict__ Bw,
    float* __restrict__ C, int M, int N, int K)
{
    __shared__ h16 As[2][128][64];
    __shared__ h16 Bs[2][128][64];
    const int tid  = threadIdx.x;
    const int wave = tid >> 6, lane = tid & 63;
    const int lr = lane & 15, lg = lane >> 4;
    const int wm = wave >> 1, wn = wave & 1;
    const int xr = blockIdx.x & 7, jr = blockIdx.x >> 3;
    const int bm = ((xr >> 1) << 3) + (jr & 7);
    const int bn = ((xr & 1) << 2) + (jr >> 3);
    const int m0 = bm << 7, n0 = bn << 7;

    f32x4 acc[4][4];
#pragma unroll
    for (int i = 0; i < 4; ++i)
#pragma unroll
        for (int j = 0; j < 4; ++j) acc[i][j] = (f32x4){0.f, 0.f, 0.f, 0.f};

    const int arow = lane >> 3;
    const int acol = (lane & 7) << 3;

#define GSTAGE(buf, k0_) do {                                                      \
    _Pragma("unroll")                                                              \
    for (int q_ = 0; q_ < 4; ++q_) {                                               \
        int ch_ = wave * 4 + q_;                                                   \
        const h16* ga_ = A + (size_t)(m0 + ch_ * 8 + arow) * K + (k0_) + acol;     \
        __builtin_amdgcn_global_load_lds(                                          \
            (const __attribute__((address_space(1))) void*)ga_,                    \
            (__attribute__((address_space(3))) void*)(&As[buf][ch_ * 8][0]), 16, 0, 0); \
        const h16* gb_ = Bw + (size_t)(n0 + ch_ * 8 + arow) * K + (k0_) + acol;    \
        __builtin_amdgcn_global_load_lds(                                          \
            (const __attribute__((address_space(1))) void*)gb_,                    \
            (__attribute__((address_space(3))) void*)(&Bs[buf][ch_ * 8][0]), 16, 0, 0); \
    }                                                                              \
} while (0)

    const int NT = K >> 6;
    GSTAGE(0, 0);
    int cur = 0;
    for (int t = 0; t < NT; ++t) {
        const bool pf = (t + 1 < NT);
        if (pf) GSTAGE(cur ^ 1, (t + 1) << 6);
        if (pf) asm volatile("s_waitcnt vmcnt(8)" ::: "memory");
        else    asm volatile("s_waitcnt vmcnt(0)" ::: "memory");
        CBAR();
#pragma unroll
        for (int ks = 0; ks < 2; ++ks) {
            h16x8 af[4], bf[4];
#pragma unroll
            for (int mi = 0; mi < 4; ++mi)
                af[mi] = *(const h16x8*)&As[cur][wm * 64 + mi * 16 + lr][ks * 32 + lg * 8];
#pragma unroll
            for (int ni = 0; ni < 4; ++ni)
                bf[ni] = *(const h16x8*)&Bs[cur][wn * 64 + ni * 16 + lr][ks * 32 + lg * 8];
            __builtin_amdgcn_s_setprio(1);
#pragma unroll
            for (int mi = 0; mi < 4; ++mi)
#pragma unroll
                for (int ni = 0; ni < 4; ++ni)
                    acc[mi][ni] = __builtin_amdgcn_mfma_f32_16x16x32_f16(
                        af[mi], bf[ni], acc[mi][ni], 0, 0, 0);
            __builtin_amdgcn_s_setprio(0);
        }
        CBAR();
        cur ^= 1;
    }
#undef GSTAGE

#pragma unroll
    for (int mi = 0; mi < 4; ++mi)
#pragma unroll
        for (int i = 0; i < 4; ++i) {
            int row = m0 + wm * 64 + mi * 16 + lg * 4 + i;
#pragma unroll
            for (int ni = 0; ni < 4; ++ni) {
                int col = n0 + wn * 64 + ni * 16 + lr;
                C[(size_t)row * N + col] = acc[mi][ni][i];
            }
        }
}

// ---------------- causal flash attention: 8-wave paired-q-tile, head-per-XCD swizzle,
//                  T15 deferred-PV (PV of tile t-1 overlaps softmax of tile t) ----------------
// V triple-buffered: PV(t-1) reads vbuf (t-1)%3 while staging writes (t+1)%3 (disjoint).
__global__ __launch_bounds__(512) void attn_k(
    const h16* __restrict__ QKV, h16* __restrict__ O)
{
    __shared__ h16 Ks[2][64][64];   // K tile, chunk-XOR-swizzled rows (double-buffered)
    __shared__ h16 Vt[3][64][72];   // V^T tile [d][kv], stride 72 (TRIPLE-buffered)

    const int L = blockIdx.x;
    const int j = L >> 3;
    const int bx = j & 7;
    const int by = (L & 7) + ((j >> 3) << 3);   // head-per-XCD: head's 8 blocks on one XCD
    const int b = by >> 4, h = by & 15;
    const int tid = threadIdx.x, wave = tid >> 6, lane = tid & 63;
    const int lq = lane & 31, hi = lane >> 5;
    const int qlo = bx, qhi = 15 - bx;

    const h16* Qb = QKV + (size_t)b * SEQ * QKVLD + h * HD;
    const h16* Kb = Qb + DIM;
    const h16* Vb = Qb + 2 * DIM;

    const int qw0 = (wave < 4) ? (qlo * 128 + wave * 32)
                               : (qhi * 128 + (wave - 4) * 32);

    h16x8 qf[4];
    {
        const h16* qp = Qb + (size_t)(qw0 + lq) * QKVLD + 8 * hi;
        const h16 qs = (h16)(0.125f * 1.44269504f);
#pragma unroll
        for (int kb = 0; kb < 4; ++kb) {
            qf[kb] = *(const h16x8*)(qp + 16 * kb);
            qf[kb] *= qs;
        }
    }

    float l_run = 0.f;
    f32x16 accd[2];
#pragma unroll
    for (int i = 0; i < 16; ++i) { accd[0][i] = 0.f; accd[1][i] = 0.f; }

    const int kwave = wave - 4;
    const int kr = (tid & 255) >> 3, kc = tid & 7;
    h16x8 vv0, vv1;
    h16x8 pfprev[4];
    bool act_prev = false;
#pragma unroll
    for (int i = 0; i < 4; ++i) pfprev[i] = (h16x8){0,0,0,0,0,0,0,0};

#define STAGE_K(bufi, kv0_) do {                                                   \
    const h16* gk0_ = Kb + (size_t)((kv0_) + kr) * QKVLD + ((kc ^ (kr & 7)) << 3); \
    __builtin_amdgcn_global_load_lds(                                              \
        (const __attribute__((address_space(1))) void*)gk0_,                       \
        (__attribute__((address_space(3))) void*)(&Ks[bufi][kwave * 8][0]), 16, 0, 0); \
    const h16* gk1_ = Kb + (size_t)((kv0_) + 32 + kr) * QKVLD + ((kc ^ (kr & 7)) << 3); \
    __builtin_amdgcn_global_load_lds(                                              \
        (const __attribute__((address_space(1))) void*)gk1_,                       \
        (__attribute__((address_space(3))) void*)(&Ks[bufi][32 + kwave * 8][0]), 16, 0, 0); \
} while (0)

#define VLOAD(kv0_) do {                                                           \
    const h16* gv_ = Vb + (size_t)((kv0_) + lane) * QKVLD + 16 * wave;             \
    vv0 = *(const h16x8*)gv_; vv1 = *(const h16x8*)(gv_ + 8);                      \
} while (0)

#define VWRITE(bufi) do {                                                          \
    _Pragma("unroll")                                                              \
    for (int j_ = 0; j_ < 8; ++j_) {                                               \
        Vt[bufi][16 * wave + j_][lane] = vv0[j_];                                  \
        Vt[bufi][16 * wave + 8 + j_][lane] = vv1[j_];                              \
    }                                                                              \
} while (0)

    const int nkv = 2 * qhi + 2;
    if (wave >= 4) STAGE_K(0, 0);
    else { VLOAD(0); VWRITE(0); }
    __syncthreads();

    int vcur = 0;                     // V buffer holding tile t
    for (int t = 0; t < nkv; ++t) {
        const int cur = t & 1;
        const int kv0 = t << 6;
        const bool pf = (t + 1 < nkv);
        const int vprev = vcur ? (vcur - 1) : 2;
        const int vnext = (vcur == 2) ? 0 : (vcur + 1);
        if (pf) {
            if (wave >= 4) STAGE_K(cur ^ 1, kv0 + 64);
            else VLOAD(kv0 + 64);
        }

        const bool act = (kv0 <= qw0 + 31);     // wave-uniform, prefix in t
        f32x16 s0, s1;
        if (act) {
            // ---- QK^T(t): S^T = K Q^T ----
#pragma unroll
            for (int i = 0; i < 16; ++i) { s0[i] = 0.f; s1[i] = 0.f; }
            const int sk = lq & 7;
            __builtin_amdgcn_s_setprio(1);
#pragma unroll
            for (int kb = 0; kb < 4; ++kb) {
                const int ch = ((2 * kb + hi) ^ sk) << 3;
                h16x8 kf0 = *(const h16x8*)&Ks[cur][lq][ch];
                h16x8 kf1 = *(const h16x8*)&Ks[cur][32 + lq][ch];
                s0 = __builtin_amdgcn_mfma_f32_32x32x16_f16(kf0, qf[kb], s0, 0, 0, 0);
                s1 = __builtin_amdgcn_mfma_f32_32x32x16_f16(kf1, qf[kb], s1, 0, 0, 0);
            }
            __builtin_amdgcn_s_setprio(0);
        }
        // ---- deferred PV(t-1): independent of s0/s1; overlaps softmax below ----
        if (act_prev) {
            __builtin_amdgcn_s_setprio(1);
#pragma unroll
            for (int da = 0; da < 2; ++da)
#pragma unroll
                for (int kvb = 0; kvb < 4; ++kvb) {
                    h16x8 vf = *(const h16x8*)&Vt[vprev][32 * da + lq][16 * kvb + 8 * hi];
                    accd[da] = __builtin_amdgcn_mfma_f32_32x32x16_f16(vf, pfprev[kvb], accd[da], 0, 0, 0);
                }
            __builtin_amdgcn_s_setprio(0);
        }
        if (act) {
            // ---- softmax(t): P = 2^S (m=0, unnormalized); mask only diagonal tile ----
            const bool full = (kv0 + 64 <= qw0);
            float p[32];
            if (full) {
#pragma unroll
                for (int r = 0; r < 16; ++r) {
                    p[r]      = exp2f(s0[r]);
                    p[16 + r] = exp2f(s1[r]);
                }
            } else {
                const int Lq = qw0 + lq - kv0;
#pragma unroll
                for (int r = 0; r < 16; ++r) {
                    const int kvl = (r & 3) + 8 * (r >> 2) + 4 * hi;
                    float e0 = exp2f(s0[r]);
                    float e1 = exp2f(s1[r]);
                    p[r]      = (kvl <= Lq)      ? e0 : 0.f;
                    p[16 + r] = (kvl + 32 <= Lq) ? e1 : 0.f;
                }
            }
            // ---- pack to f16 pairs; l-sum via dot2 on pre-swap pairs; permlane to B-frag ----
            float ls = 0.f;
            const fp16x2 one2 = {(__fp16)1.0f, (__fp16)1.0f};
#pragma unroll
            for (int kva = 0; kva < 2; ++kva) {
                const int o = 16 * kva;
                U2 x, y, z, w, x2, y2, z2, w2;
                x.g  = __builtin_amdgcn_cvt_pkrtz(p[o+0],  p[o+1]);
                y.g  = __builtin_amdgcn_cvt_pkrtz(p[o+2],  p[o+3]);
                z.g  = __builtin_amdgcn_cvt_pkrtz(p[o+4],  p[o+5]);
                w.g  = __builtin_amdgcn_cvt_pkrtz(p[o+6],  p[o+7]);
                x2.g = __builtin_amdgcn_cvt_pkrtz(p[o+8],  p[o+9]);
                y2.g = __builtin_amdgcn_cvt_pkrtz(p[o+10], p[o+11]);
                z2.g = __builtin_amdgcn_cvt_pkrtz(p[o+12], p[o+13]);
                w2.g = __builtin_amdgcn_cvt_pkrtz(p[o+14], p[o+15]);
#if __has_builtin(__builtin_amdgcn_fdot2)
                ls = __builtin_amdgcn_fdot2(x.g,  one2, ls, false);
                ls = __builtin_amdgcn_fdot2(y.g,  one2, ls, false);
                ls = __builtin_amdgcn_fdot2(z.g,  one2, ls, false);
                ls = __builtin_amdgcn_fdot2(w.g,  one2, ls, false);
                ls = __builtin_amdgcn_fdot2(x2.g, one2, ls, false);
                ls = __builtin_amdgcn_fdot2(y2.g, one2, ls, false);
                ls = __builtin_amdgcn_fdot2(z2.g, one2, ls, false);
                ls = __builtin_amdgcn_fdot2(w2.g, one2, ls, false);
#else
                ls += p[o+0]+p[o+1]+p[o+2]+p[o+3]+p[o+4]+p[o+5]+p[o+6]+p[o+7]
                    + p[o+8]+p[o+9]+p[o+10]+p[o+11]+p[o+12]+p[o+13]+p[o+14]+p[o+15];
#endif
                asm volatile("v_permlane32_swap_b32 %0, %1" : "+v"(x.u),  "+v"(z.u));
                asm volatile("v_permlane32_swap_b32 %0, %1" : "+v"(y.u),  "+v"(w.u));
                asm volatile("v_permlane32_swap_b32 %0, %1" : "+v"(x2.u), "+v"(z2.u));
                asm volatile("v_permlane32_swap_b32 %0, %1" : "+v"(y2.u), "+v"(w2.u));
                h16x8 f0, f1;
                f0[0]=x.h.x;  f0[1]=x.h.y;  f0[2]=y.h.x;  f0[3]=y.h.y;
                f0[4]=z.h.x;  f0[5]=z.h.y;  f0[6]=w.h.x;  f0[7]=w.h.y;
                f1[0]=x2.h.x; f1[1]=x2.h.y; f1[2]=y2.h.x; f1[3]=y2.h.y;
                f1[4]=z2.h.x; f1[5]=z2.h.y; f1[6]=w2.h.x; f1[7]=w2.h.y;
                pfprev[2*kva]   = f0;
                pfprev[2*kva+1] = f1;
            }
            l_run += ls;
        }
        act_prev = act;
        if (pf && wave < 4) VWRITE(vnext);
        __syncthreads();
        vcur = vnext;
    }

    // ---- drain: PV of the last active tile ----
    if (act_prev) {
        const int vlast = vcur ? (vcur - 1) : 2;   // buffer of tile nkv-1
        __builtin_amdgcn_s_setprio(1);
#pragma unroll
        for (int da = 0; da < 2; ++da)
#pragma unroll
            for (int kvb = 0; kvb < 4; ++kvb) {
                h16x8 vf = *(const h16x8*)&Vt[vlast][32 * da + lq][16 * kvb + 8 * hi];
                accd[da] = __builtin_amdgcn_mfma_f32_32x32x16_f16(vf, pfprev[kvb], accd[da], 0, 0, 0);
            }
        __builtin_amdgcn_s_setprio(0);
    }

    float lt = l_run + __shfl_xor(l_run, 32);
    float inv = 1.0f / lt;
    h16* Ob = O + (size_t)b * SEQ * DIM + h * HD + (size_t)(qw0 + lq) * DIM;
#pragma unroll
    for (int da = 0; da < 2; ++da)
#pragma unroll
        for (int r = 0; r < 16; r += 2) {
            int d = 32 * da + (r & 3) + 8 * (r >> 2) + 4 * hi;
            h16x2 ov;
            ov.x = (h16)(accd[da][r] * inv);
            ov.y = (h16)(accd[da][r + 1] * inv);
            *(h16x2*)(Ob + d) = ov;
        }
#undef STAGE_K
#undef VLOAD
#undef VWRITE
}

extern "C" void kernel_launch(void* const* d_in, const int* in_sizes, int n_in,
                              void* d_out, int out_size, void* d_ws, size_t ws_size,
                              hipStream_t stream)
{
    const float* x  = (const float*)d_in[0];
    const float* Wq = (const float*)d_in[1];
    const float* Wk = (const float*)d_in[2];
    const float* Wv = (const float*)d_in[3];
    const float* Wo = (const float*)d_in[4];

    char* ws = (char*)d_ws;
    h16* xh     = (h16*)(ws);                           // 8 MB
    h16* wqkvh  = (h16*)(ws + ((size_t)8  << 20));      // 6 MB packed [3072][1024]
    h16* woh    = (h16*)(ws + ((size_t)14 << 20));      // 2 MB
    h16* QKVd   = (h16*)(ws + ((size_t)16 << 20));      // 24 MB [4096][3072]
    h16* Od     = (h16*)(ws + ((size_t)40 << 20));      // 8 MB
    float2* rope = (float2*)(ws + ((size_t)48 << 20));  // 512 KB

    const int NX = MROWS * DIM / 4, NW = DIM * DIM / 4;
    prep_k<<<(NX + 4 * NW + SEQ * 32) / 256, 256, 0, stream>>>(
        x, Wq, Wk, Wv, Wo, xh, wqkvh, woh, rope);

    gemm256_qkv<<<(MROWS / 256) * (QKVLD / 256), 512, 0, stream>>>(
        xh, wqkvh, QKVd, rope);

    attn_k<<<256, 512, 0, stream>>>(QKVd, Od);

    gemm_out<<<(MROWS / 128) * (DIM / 128), 256, 0, stream>>>(
        Od, woh, (float*)d_out, MROWS, DIM, DIM);
}

// Round 15
// 121.158 us; speedup vs baseline: 1.1238x; 1.1238x over previous
//
#include <hip/hip_runtime.h>

#define DIM 1024
#define NHEADS 16
#define HD 64
#define SEQ 2048
#define BATCH 2
#define MROWS (BATCH*SEQ)
#define QKVLD 3072

typedef _Float16 h16;
typedef __attribute__((ext_vector_type(2))) _Float16 h16x2;
typedef __attribute__((ext_vector_type(2))) __fp16 fp16x2;
typedef __attribute__((ext_vector_type(4))) _Float16 h16x4;
typedef __attribute__((ext_vector_type(8))) _Float16 h16x8;
typedef __attribute__((ext_vector_type(4))) float f32x4;
typedef __attribute__((ext_vector_type(16))) float f32x16;

union U2 { fp16x2 g; h16x2 h; unsigned u; };

#define CBAR() do { asm volatile("" ::: "memory"); __builtin_amdgcn_s_barrier(); \
                    asm volatile("" ::: "memory"); } while (0)

// ---------------- fused prep: cvt x, cvt weights (packed QKV), rope table ----------------
__global__ __launch_bounds__(256) void prep_k(
    const float* __restrict__ x,  const float* __restrict__ wq,
    const float* __restrict__ wk, const float* __restrict__ wv,
    const float* __restrict__ wo,
    h16* __restrict__ xh, h16* __restrict__ wqkvh, h16* __restrict__ woh,
    float2* __restrict__ rope)
{
    const int NX = MROWS * DIM / 4;      // 1048576
    const int NW = DIM * DIM / 4;        // 262144 = 2^18
    int gid = blockIdx.x * 256 + threadIdx.x;
    if (gid < NX) {
        float4 v = *reinterpret_cast<const float4*>(x + (size_t)gid * 4);
        h16x4 o; o.x=(h16)v.x; o.y=(h16)v.y; o.z=(h16)v.z; o.w=(h16)v.w;
        *reinterpret_cast<h16x4*>(xh + (size_t)gid * 4) = o;
    } else if (gid < NX + 3 * NW) {
        int j = gid - NX;
        int w = j >> 18, e = j & (NW - 1);
        const float* s = (w == 0) ? wq : (w == 1) ? wk : wv;
        float4 v = *reinterpret_cast<const float4*>(s + (size_t)e * 4);
        h16x4 o; o.x=(h16)v.x; o.y=(h16)v.y; o.z=(h16)v.z; o.w=(h16)v.w;
        *reinterpret_cast<h16x4*>(wqkvh + (size_t)w * DIM * DIM + (size_t)e * 4) = o;
    } else if (gid < NX + 4 * NW) {
        int e = gid - NX - 3 * NW;
        float4 v = *reinterpret_cast<const float4*>(wo + (size_t)e * 4);
        h16x4 o; o.x=(h16)v.x; o.y=(h16)v.y; o.z=(h16)v.z; o.w=(h16)v.w;
        *reinterpret_cast<h16x4*>(woh + (size_t)e * 4) = o;
    } else {
        int t = gid - NX - 4 * NW;      // 0..65535
        int s = t >> 5, j = t & 31;
        float inv = powf(10000.0f, -(float)j / 32.0f);
        float ang = (float)s * inv;
        rope[t] = make_float2(cosf(ang), sinf(ang));
    }
}

// ---------------- QKV GEMM: 256x256 tile, 8-wave, deep counted-vmcnt pipeline (R12-verified) ----------------
__global__ __launch_bounds__(512, 1) void gemm256_qkv(
    const h16* __restrict__ A, const h16* __restrict__ Bw,
    h16* __restrict__ C, const float2* __restrict__ rope)
{
    __shared__ h16 As[2][256][64];   // 64 KB
    __shared__ h16 Bs[2][256][64];   // 64 KB
    const int tid = threadIdx.x, wave = tid >> 6, lane = tid & 63;
    const int lr = lane & 15, lg = lane >> 4;
    const int wm = wave >> 2, wn = wave & 3;          // 2 x 4 wave grid
    const int xr = blockIdx.x & 7, jr = blockIdx.x >> 3;   // rect-per-XCD
    const int bm = ((xr >> 1) << 2) + (jr & 3);
    const int bn = (xr & 1) * 6 + (jr >> 2);
    const int m0 = bm << 8, n0 = bn << 8;

    const int srl = lane >> 3;            // 0..7
    const int sgc = ((lane & 7) ^ srl) << 3;

#define STAGE_HALF(buf, k0_, h_) do {                                               \
    _Pragma("unroll")                                                               \
    for (int j_ = 0; j_ < 2; ++j_) {                                                \
        int rl_ = ((h_) & 1) * 128 + (j_ * 8 + wave) * 8;                           \
        if ((h_) < 2) {                                                             \
            const h16* g_ = A + (size_t)(m0 + rl_ + srl) * DIM + (k0_) + sgc;       \
            __builtin_amdgcn_global_load_lds(                                       \
                (const __attribute__((address_space(1))) void*)g_,                  \
                (__attribute__((address_space(3))) void*)(&As[buf][rl_][0]), 16, 0, 0); \
        } else {                                                                    \
            const h16* g_ = Bw + (size_t)(n0 + rl_ + srl) * DIM + (k0_) + sgc;      \
            __builtin_amdgcn_global_load_lds(                                       \
                (const __attribute__((address_space(1))) void*)g_,                  \
                (__attribute__((address_space(3))) void*)(&Bs[buf][rl_][0]), 16, 0, 0); \
        }                                                                           \
    }                                                                               \
} while (0)

    f32x4 acc[8][4];
#pragma unroll
    for (int i = 0; i < 8; ++i)
#pragma unroll
        for (int j = 0; j < 4; ++j) acc[i][j] = (f32x4){0.f, 0.f, 0.f, 0.f};

    const int NT = DIM >> 6;   // 16
#pragma unroll
    for (int h = 0; h < 4; ++h) STAGE_HALF(0, 0, h);

    int cur = 0;
    for (int t = 0; t < NT; ++t) {
        const int k0n = (t + 1) << 6;
        const bool pf = (t + 1 < NT);
        if (pf) {
#pragma unroll
            for (int h = 0; h < 4; ++h) STAGE_HALF(cur ^ 1, k0n, h);
        }
        if (pf) asm volatile("s_waitcnt vmcnt(8)" ::: "memory");
        else    asm volatile("s_waitcnt vmcnt(0)" ::: "memory");
        CBAR();
        h16x8 bfr[4][2];
#pragma unroll
        for (int ni = 0; ni < 4; ++ni)
#pragma unroll
            for (int ks = 0; ks < 2; ++ks) {
                int r = wn * 64 + ni * 16 + lr;
                int cpos = ((ks << 2) + lg) ^ (lr & 7);
                bfr[ni][ks] = *(const h16x8*)&Bs[cur][r][cpos << 3];
            }
#pragma unroll
        for (int half = 0; half < 2; ++half) {
            h16x8 afr[4][2];
#pragma unroll
            for (int e = 0; e < 4; ++e)
#pragma unroll
                for (int ks = 0; ks < 2; ++ks) {
                    int r = wm * 128 + (half * 4 + e) * 16 + lr;
                    int cpos = ((ks << 2) + lg) ^ (lr & 7);
                    afr[e][ks] = *(const h16x8*)&As[cur][r][cpos << 3];
                }
            __builtin_amdgcn_s_setprio(1);
#pragma unroll
            for (int e = 0; e < 4; ++e)
#pragma unroll
                for (int ni = 0; ni < 4; ++ni)
#pragma unroll
                    for (int ks = 0; ks < 2; ++ks)
                        acc[half * 4 + e][ni] = __builtin_amdgcn_mfma_f32_16x16x32_f16(
                            afr[e][ks], bfr[ni][ks], acc[half * 4 + e][ni], 0, 0, 0);
            __builtin_amdgcn_s_setprio(0);
        }
        CBAR();
        cur ^= 1;
    }
#undef STAGE_HALF

    const int region = n0 >> 10;       // 0=Q, 1=K, 2=V
    if (region == 2) {
#pragma unroll
        for (int mi = 0; mi < 8; ++mi)
#pragma unroll
            for (int i = 0; i < 4; ++i) {
                int row = m0 + wm * 128 + mi * 16 + lg * 4 + i;
#pragma unroll
                for (int ni = 0; ni < 4; ++ni) {
                    int col = n0 + wn * 64 + ni * 16 + lr;
                    C[(size_t)row * QKVLD + col] = (h16)acc[mi][ni][i];
                }
            }
    } else {
#pragma unroll
        for (int mi = 0; mi < 8; ++mi)
#pragma unroll
            for (int i = 0; i < 4; ++i) {
                int row = m0 + wm * 128 + mi * 16 + lg * 4 + i;
                int s = row & (SEQ - 1);
#pragma unroll
                for (int ni = 0; ni < 4; ++ni) {
                    int col = n0 + wn * 64 + ni * 16 + lr;
                    int d = col & 63;
                    float2 cs = rope[(s << 5) + (d & 31)];
                    float v  = acc[mi][ni][i];
                    float vp = acc[mi][ni ^ 2][i];
                    float rh = (d < 32) ? -vp : vp;
                    C[(size_t)row * QKVLD + col] = (h16)(v * cs.x + rh * cs.y);
                }
            }
    }
}

// ---------------- out-proj GEMM: 128x128, deep burst pipeline + rect swizzle (R13-verified) ----------------
__global__ __launch_bounds__(256) void gemm_out(
    const h16* __restrict__ A, const h16* __restrict__ Bw,
    float* __restrict__ C, int M, int N, int K)
{
    __shared__ h16 As[2][128][64];
    __shared__ h16 Bs[2][128][64];
    const int tid  = threadIdx.x;
    const int wave = tid >> 6, lane = tid & 63;
    const int lr = lane & 15, lg = lane >> 4;
    const int wm = wave >> 1, wn = wave & 1;
    const int xr = blockIdx.x & 7, jr = blockIdx.x >> 3;
    const int bm = ((xr >> 1) << 3) + (jr & 7);
    const int bn = ((xr & 1) << 2) + (jr >> 3);
    const int m0 = bm << 7, n0 = bn << 7;

    f32x4 acc[4][4];
#pragma unroll
    for (int i = 0; i < 4; ++i)
#pragma unroll
        for (int j = 0; j < 4; ++j) acc[i][j] = (f32x4){0.f, 0.f, 0.f, 0.f};

    const int arow = lane >> 3;
    const int acol = (lane & 7) << 3;

#define GSTAGE(buf, k0_) do {                                                      \
    _Pragma("unroll")                                                              \
    for (int q_ = 0; q_ < 4; ++q_) {                                               \
        int ch_ = wave * 4 + q_;                                                   \
        const h16* ga_ = A + (size_t)(m0 + ch_ * 8 + arow) * K + (k0_) + acol;     \
        __builtin_amdgcn_global_load_lds(                                          \
            (const __attribute__((address_space(1))) void*)ga_,                    \
            (__attribute__((address_space(3))) void*)(&As[buf][ch_ * 8][0]), 16, 0, 0); \
        const h16* gb_ = Bw + (size_t)(n0 + ch_ * 8 + arow) * K + (k0_) + acol;    \
        __builtin_amdgcn_global_load_lds(                                          \
            (const __attribute__((address_space(1))) void*)gb_,                    \
            (__attribute__((address_space(3))) void*)(&Bs[buf][ch_ * 8][0]), 16, 0, 0); \
    }                                                                              \
} while (0)

    const int NT = K >> 6;
    GSTAGE(0, 0);
    int cur = 0;
    for (int t = 0; t < NT; ++t) {
        const bool pf = (t + 1 < NT);
        if (pf) GSTAGE(cur ^ 1, (t + 1) << 6);
        if (pf) asm volatile("s_waitcnt vmcnt(8)" ::: "memory");
        else    asm volatile("s_waitcnt vmcnt(0)" ::: "memory");
        CBAR();
#pragma unroll
        for (int ks = 0; ks < 2; ++ks) {
            h16x8 af[4], bf[4];
#pragma unroll
            for (int mi = 0; mi < 4; ++mi)
                af[mi] = *(const h16x8*)&As[cur][wm * 64 + mi * 16 + lr][ks * 32 + lg * 8];
#pragma unroll
            for (int ni = 0; ni < 4; ++ni)
                bf[ni] = *(const h16x8*)&Bs[cur][wn * 64 + ni * 16 + lr][ks * 32 + lg * 8];
            __builtin_amdgcn_s_setprio(1);
#pragma unroll
            for (int mi = 0; mi < 4; ++mi)
#pragma unroll
                for (int ni = 0; ni < 4; ++ni)
                    acc[mi][ni] = __builtin_amdgcn_mfma_f32_16x16x32_f16(
                        af[mi], bf[ni], acc[mi][ni], 0, 0, 0);
            __builtin_amdgcn_s_setprio(0);
        }
        CBAR();
        cur ^= 1;
    }
#undef GSTAGE

#pragma unroll
    for (int mi = 0; mi < 4; ++mi)
#pragma unroll
        for (int i = 0; i < 4; ++i) {
            int row = m0 + wm * 64 + mi * 16 + lg * 4 + i;
#pragma unroll
            for (int ni = 0; ni < 4; ++ni) {
                int col = n0 + wn * 64 + ni * 16 + lr;
                C[(size_t)row * N + col] = acc[mi][ni][i];
            }
        }
}

// ---------------- causal flash attention: 8-wave paired-q-tile, KVBLK=64, head-per-XCD swizzle
//                  (R13-verified structure) + fdot2 l-sum (R14 salvage) ----------------
__global__ __launch_bounds__(512) void attn_k(
    const h16* __restrict__ QKV, h16* __restrict__ O)
{
    __shared__ h16 Ks[2][64][64];   // K tile, chunk-XOR-swizzled rows (128B)
    __shared__ h16 Vt[2][64][72];   // V^T tile [d][kv], stride 72

    const int L = blockIdx.x;
    const int j = L >> 3;
    const int bx = j & 7;
    const int by = (L & 7) + ((j >> 3) << 3);   // head-per-XCD: head's 8 blocks on one XCD
    const int b = by >> 4, h = by & 15;
    const int tid = threadIdx.x, wave = tid >> 6, lane = tid & 63;
    const int lq = lane & 31, hi = lane >> 5;
    const int qlo = bx, qhi = 15 - bx;

    const h16* Qb = QKV + (size_t)b * SEQ * QKVLD + h * HD;
    const h16* Kb = Qb + DIM;
    const h16* Vb = Qb + 2 * DIM;

    const int qw0 = (wave < 4) ? (qlo * 128 + wave * 32)
                               : (qhi * 128 + (wave - 4) * 32);

    h16x8 qf[4];
    {
        const h16* qp = Qb + (size_t)(qw0 + lq) * QKVLD + 8 * hi;
        const h16 qs = (h16)(0.125f * 1.44269504f);
#pragma unroll
        for (int kb = 0; kb < 4; ++kb) {
            qf[kb] = *(const h16x8*)(qp + 16 * kb);
            qf[kb] *= qs;
        }
    }

    float l_run = 0.f;
    f32x16 accd[2];
#pragma unroll
    for (int i = 0; i < 16; ++i) { accd[0][i] = 0.f; accd[1][i] = 0.f; }

    const int kwave = wave - 4;
    const int kr = (tid & 255) >> 3, kc = tid & 7;
    h16x8 vv0, vv1;

#define STAGE_K(bufi, kv0_) do {                                                   \
    const h16* gk0_ = Kb + (size_t)((kv0_) + kr) * QKVLD + ((kc ^ (kr & 7)) << 3); \
    __builtin_amdgcn_global_load_lds(                                              \
        (const __attribute__((address_space(1))) void*)gk0_,                       \
        (__attribute__((address_space(3))) void*)(&Ks[bufi][kwave * 8][0]), 16, 0, 0); \
    const h16* gk1_ = Kb + (size_t)((kv0_) + 32 + kr) * QKVLD + ((kc ^ (kr & 7)) << 3); \
    __builtin_amdgcn_global_load_lds(                                              \
        (const __attribute__((address_space(1))) void*)gk1_,                       \
        (__attribute__((address_space(3))) void*)(&Ks[bufi][32 + kwave * 8][0]), 16, 0, 0); \
} while (0)

#define VLOAD(kv0_) do {                                                           \
    const h16* gv_ = Vb + (size_t)((kv0_) + lane) * QKVLD + 16 * wave;             \
    vv0 = *(const h16x8*)gv_; vv1 = *(const h16x8*)(gv_ + 8);                      \
} while (0)

#define VWRITE(bufi) do {                                                          \
    _Pragma("unroll")                                                              \
    for (int j_ = 0; j_ < 8; ++j_) {                                               \
        Vt[bufi][16 * wave + j_][lane] = vv0[j_];                                  \
        Vt[bufi][16 * wave + 8 + j_][lane] = vv1[j_];                              \
    }                                                                              \
} while (0)

    const int nkv = 2 * qhi + 2;
    if (wave >= 4) STAGE_K(0, 0);
    else { VLOAD(0); VWRITE(0); }
    __syncthreads();

    for (int t = 0; t < nkv; ++t) {
        const int cur = t & 1;
        const int kv0 = t << 6;
        const bool pf = (t + 1 < nkv);
        if (pf) {
            if (wave >= 4) STAGE_K(cur ^ 1, kv0 + 64);
            else VLOAD(kv0 + 64);
        }

        const bool act = (kv0 <= qw0 + 31);
        h16x8 pfrag[4];
        float ls = 0.f;
        if (act) {
            // ---- S^T = K Q^T ----
            f32x16 s0, s1;
#pragma unroll
            for (int i = 0; i < 16; ++i) { s0[i] = 0.f; s1[i] = 0.f; }
            const int sk = lq & 7;
            __builtin_amdgcn_s_setprio(1);
#pragma unroll
            for (int kb = 0; kb < 4; ++kb) {
                const int ch = ((2 * kb + hi) ^ sk) << 3;
                h16x8 kf0 = *(const h16x8*)&Ks[cur][lq][ch];
                h16x8 kf1 = *(const h16x8*)&Ks[cur][32 + lq][ch];
                s0 = __builtin_amdgcn_mfma_f32_32x32x16_f16(kf0, qf[kb], s0, 0, 0, 0);
                s1 = __builtin_amdgcn_mfma_f32_32x32x16_f16(kf1, qf[kb], s1, 0, 0, 0);
            }
            __builtin_amdgcn_s_setprio(0);
            // ---- P = 2^S (m=0, unnormalized); mask only the diagonal tile ----
            const bool full = (kv0 + 64 <= qw0);
            float p[32];
            if (full) {
#pragma unroll
                for (int r = 0; r < 16; ++r) {
                    p[r]      = exp2f(s0[r]);
                    p[16 + r] = exp2f(s1[r]);
                }
            } else {
                const int Lq = qw0 + lq - kv0;
#pragma unroll
                for (int r = 0; r < 16; ++r) {
                    const int kvl = (r & 3) + 8 * (r >> 2) + 4 * hi;
                    float e0 = exp2f(s0[r]);
                    float e1 = exp2f(s1[r]);
                    p[r]      = (kvl <= Lq)      ? e0 : 0.f;
                    p[16 + r] = (kvl + 32 <= Lq) ? e1 : 0.f;
                }
            }
            // ---- pack to f16 pairs; l-sum via fdot2 on pre-swap pairs; permlane to B-frag ----
            const fp16x2 one2 = {(__fp16)1.0f, (__fp16)1.0f};
#pragma unroll
            for (int kva = 0; kva < 2; ++kva) {
                const int o = 16 * kva;
                U2 x, y, z, w, x2, y2, z2, w2;
                x.g  = __builtin_amdgcn_cvt_pkrtz(p[o+0],  p[o+1]);
                y.g  = __builtin_amdgcn_cvt_pkrtz(p[o+2],  p[o+3]);
                z.g  = __builtin_amdgcn_cvt_pkrtz(p[o+4],  p[o+5]);
                w.g  = __builtin_amdgcn_cvt_pkrtz(p[o+6],  p[o+7]);
                x2.g = __builtin_amdgcn_cvt_pkrtz(p[o+8],  p[o+9]);
                y2.g = __builtin_amdgcn_cvt_pkrtz(p[o+10], p[o+11]);
                z2.g = __builtin_amdgcn_cvt_pkrtz(p[o+12], p[o+13]);
                w2.g = __builtin_amdgcn_cvt_pkrtz(p[o+14], p[o+15]);
#if __has_builtin(__builtin_amdgcn_fdot2)
                ls = __builtin_amdgcn_fdot2(x.g,  one2, ls, false);
                ls = __builtin_amdgcn_fdot2(y.g,  one2, ls, false);
                ls = __builtin_amdgcn_fdot2(z.g,  one2, ls, false);
                ls = __builtin_amdgcn_fdot2(w.g,  one2, ls, false);
                ls = __builtin_amdgcn_fdot2(x2.g, one2, ls, false);
                ls = __builtin_amdgcn_fdot2(y2.g, one2, ls, false);
                ls = __builtin_amdgcn_fdot2(z2.g, one2, ls, false);
                ls = __builtin_amdgcn_fdot2(w2.g, one2, ls, false);
#else
                ls += p[o+0]+p[o+1]+p[o+2]+p[o+3]+p[o+4]+p[o+5]+p[o+6]+p[o+7]
                    + p[o+8]+p[o+9]+p[o+10]+p[o+11]+p[o+12]+p[o+13]+p[o+14]+p[o+15];
#endif
                asm volatile("v_permlane32_swap_b32 %0, %1" : "+v"(x.u),  "+v"(z.u));
                asm volatile("v_permlane32_swap_b32 %0, %1" : "+v"(y.u),  "+v"(w.u));
                asm volatile("v_permlane32_swap_b32 %0, %1" : "+v"(x2.u), "+v"(z2.u));
                asm volatile("v_permlane32_swap_b32 %0, %1" : "+v"(y2.u), "+v"(w2.u));
                h16x8 f0, f1;
                f0[0]=x.h.x;  f0[1]=x.h.y;  f0[2]=y.h.x;  f0[3]=y.h.y;
                f0[4]=z.h.x;  f0[5]=z.h.y;  f0[6]=w.h.x;  f0[7]=w.h.y;
                f1[0]=x2.h.x; f1[1]=x2.h.y; f1[2]=y2.h.x; f1[3]=y2.h.y;
                f1[4]=z2.h.x; f1[5]=z2.h.y; f1[6]=w2.h.x; f1[7]=w2.h.y;
                pfrag[2*kva]   = f0;
                pfrag[2*kva+1] = f1;
            }
            l_run += ls;
        }
        if (pf && wave < 4) VWRITE(cur ^ 1);
        if (act) {
            // ---- O^T += V^T P^T ----
            __builtin_amdgcn_s_setprio(1);
#pragma unroll
            for (int da = 0; da < 2; ++da)
#pragma unroll
                for (int kvb = 0; kvb < 4; ++kvb) {
                    h16x8 vf = *(const h16x8*)&Vt[cur][32 * da + lq][16 * kvb + 8 * hi];
                    accd[da] = __builtin_amdgcn_mfma_f32_32x32x16_f16(vf, pfrag[kvb], accd[da], 0, 0, 0);
                }
            __builtin_amdgcn_s_setprio(0);
        }
        __syncthreads();
    }

    float lt = l_run + __shfl_xor(l_run, 32);
    float inv = 1.0f / lt;
    h16* Ob = O + (size_t)b * SEQ * DIM + h * HD + (size_t)(qw0 + lq) * DIM;
#pragma unroll
    for (int da = 0; da < 2; ++da)
#pragma unroll
        for (int r = 0; r < 16; r += 2) {
            int d = 32 * da + (r & 3) + 8 * (r >> 2) + 4 * hi;
            h16x2 ov;
            ov.x = (h16)(accd[da][r] * inv);
            ov.y = (h16)(accd[da][r + 1] * inv);
            *(h16x2*)(Ob + d) = ov;
        }
#undef STAGE_K
#undef VLOAD
#undef VWRITE
}

extern "C" void kernel_launch(void* const* d_in, const int* in_sizes, int n_in,
                              void* d_out, int out_size, void* d_ws, size_t ws_size,
                              hipStream_t stream)
{
    const float* x  = (const float*)d_in[0];
    const float* Wq = (const float*)d_in[1];
    const float* Wk = (const float*)d_in[2];
    const float* Wv = (const float*)d_in[3];
    const float* Wo = (const float*)d_in[4];

    char* ws = (char*)d_ws;
    h16* xh     = (h16*)(ws);                           // 8 MB
    h16* wqkvh  = (h16*)(ws + ((size_t)8  << 20));      // 6 MB packed [3072][1024]
    h16* woh    = (h16*)(ws + ((size_t)14 << 20));      // 2 MB
    h16* QKVd   = (h16*)(ws + ((size_t)16 << 20));      // 24 MB [4096][3072]
    h16* Od     = (h16*)(ws + ((size_t)40 << 20));      // 8 MB
    float2* rope = (float2*)(ws + ((size_t)48 << 20));  // 512 KB

    const int NX = MROWS * DIM / 4, NW = DIM * DIM / 4;
    prep_k<<<(NX + 4 * NW + SEQ * 32) / 256, 256, 0, stream>>>(
        x, Wq, Wk, Wv, Wo, xh, wqkvh, woh, rope);

    gemm256_qkv<<<(MROWS / 256) * (QKVLD / 256), 512, 0, stream>>>(
        xh, wqkvh, QKVd, rope);

    attn_k<<<256, 512, 0, stream>>>(QKVd, Od);

    gemm_out<<<(MROWS / 128) * (DIM / 128), 256, 0, stream>>>(
        Od, woh, (float*)d_out, MROWS, DIM, DIM);
}